// Round 10
// baseline (368.333 us; speedup 1.0000x reference)
//
#include <hip/hip_runtime.h>
#include <hip/hip_bf16.h>
#include <math.h>

#define Bc 2
#define Cc 16
#define D4c 48
#define Kc 24
#define Hc 512
#define Wc 960
#define H4c 128
#define W4c 240
#define HW4 (H4c * W4c)   // 30720
#define S4 (Bc * HW4)     // 61440
#define HW1 (Hc * Wc)     // 491520
#define S1 (Bc * HW1)     // 983040
#define Gg 8              // disparity groups (lanes per pixel)
#define DPT 6             // disparities per thread
#define PPB 32            // pixels per block
#define HALO 47           // max disparity reach to the left
#define RW (PPB + HALO)   // 79: Rred halo row length

// ---------------------------------------------------------------------------
// VALU-only lane-xor helpers (DPP); group dim in lane bits [2:0].
// ---------------------------------------------------------------------------
template<int CTRL, int BANK>
__device__ __forceinline__ int dpp_mov(int old_, int src) {
    return __builtin_amdgcn_update_dpp(old_, src, CTRL, 0xF, BANK, false);
}
template<int X>
__device__ __forceinline__ unsigned lxor_u(unsigned v) {
    int r = (int)v;
    if constexpr (X & 4) {
        int t = dpp_mov<0x104, 0x5>(r, r);   // row_shl:4
        r     = dpp_mov<0x114, 0xA>(t, r);   // row_shr:4
    }
    if constexpr ((X & 3) == 1) r = dpp_mov<0xB1, 0xF>(r, r);
    if constexpr ((X & 3) == 2) r = dpp_mov<0x4E, 0xF>(r, r);
    if constexpr ((X & 3) == 3) r = dpp_mov<0x1B, 0xF>(r, r);
    return (unsigned)r;
}
template<int X> __device__ __forceinline__ float lxor_f(float v) {
    return __uint_as_float(lxor_u<X>(__float_as_uint(v)));
}
template<int X> __device__ __forceinline__ int lxor_i(int v) {
    return (int)lxor_u<X>((unsigned)v);
}

template<int C>
__device__ __forceinline__ void rank_round(const unsigned (&u)[DPT], int (&bc)[DPT], int q) {
    const unsigned adj = ((q ^ C) < q) ? 1u : 0u;
    unsigned uj[DPT];
#pragma unroll
    for (int j = 0; j < DPT; ++j) uj[j] = lxor_u<C>(u[j]);
#pragma unroll
    for (int i = 0; i < DPT; ++i) {
        const unsigned ui2 = u[i] - adj;
#pragma unroll
        for (int j = 0; j < DPT; ++j) bc[i] += (uj[j] > ui2) ? 1 : 0;
    }
}

template<int X>
__device__ __forceinline__ void merge_stage(float& s, float& s2, float& n2,
                                            float& v1, int& i1, float& v2, int& i2v) {
    s  += lxor_f<X>(s);
    s2 += lxor_f<X>(s2);
    n2 += lxor_f<X>(n2);
    float ov1 = lxor_f<X>(v1); int oi1 = lxor_i<X>(i1);
    float ov2 = lxor_f<X>(v2); int oi2 = lxor_i<X>(i2v);
    bool bt = (ov1 > v1) || (ov1 == v1 && oi1 < i1);
    float w1 = bt ? ov1 : v1;   int wi1 = bt ? oi1 : i1;
    float l1 = bt ? v1  : ov1;  int li1 = bt ? i1  : oi1;
    float w2 = bt ? ov2 : v2;   int wi2 = bt ? oi2 : i2v;
    bool b2 = (l1 > w2) || (l1 == w2 && li1 < wi2);
    v1 = w1; i1 = wi1;
    v2 = b2 ? l1 : w2;
    i2v = b2 ? li1 : wi2;
}

// ---------------------------------------------------------------------------
// MODE bits: 1 = skip rank loop, 2 = skip feat/LDS stage, 4 = synth att.
// REP > 1: internal repetition with asm-opaque offset (defeats CSE) so the
// dispatch is long enough to surface in rocprof top-5 with its counters.
// ---------------------------------------------------------------------------
template<int MODE, int REP>
__global__ __launch_bounds__(256, 6) void k_topk_t(const float* __restrict__ att,
                       const float* __restrict__ fl, const float* __restrict__ fr,
                       const float* __restrict__ wred,
                       float* __restrict__ oA4, float* __restrict__ oD4) {
    __shared__ float rrow[RW];
    __shared__ float lrow[PPB];

    const int tid    = threadIdx.x;
    const int wv     = tid >> 6;
    const int lane   = tid & 63;
    const int q      = lane & 7;
    const int p      = lane >> 3;
    const int plocal = wv * 8 + p;
    const int pix0   = blockIdx.x * PPB;
    const int pix    = pix0 + plocal;
    const int b      = pix0 / HW4;
    const int hw     = pix - b * HW4;
    const int col    = hw % W4c;
    const int dbase  = q * DPT;

    float accA = 0.f, accD = 0.f;
#pragma unroll 1
    for (int rep = 0; rep < REP; ++rep) {
        int off = 0;
        if constexpr (REP > 1) {
            asm volatile("v_mov_b32 %0, %1" : "=v"(off) : "v"(rep));
        }
        int hw2 = hw + off; if (hw2 >= HW4) hw2 = HW4 - 1;

        // ---- att logits (real or synthesized) ----
        float a[DPT];
        if constexpr (!(MODE & 4)) {
            const float* ap = att + ((size_t)b * D4c + dbase) * HW4 + hw2;
#pragma unroll
            for (int i = 0; i < DPT; ++i) a[i] = ap[(size_t)i * HW4];
        } else {
            unsigned h = (unsigned)(tid + rep * 257);
#pragma unroll
            for (int i = 0; i < DPT; ++i) {
                unsigned g = (h + (unsigned)i * 65537u) * 2654435761u;
                a[i] = __uint_as_float(0x3f800000u | (g >> 10 & 0x3FFFFFu));
            }
        }

        // ---- feat channel-reduction into LDS ----
        float L; float RR[DPT];
        if constexpr (!(MODE & 2)) {
            if constexpr (REP > 1) __syncthreads();   // protect rrow reuse
            const int base = b * HW4;
            if (tid < RW) {
                int lin = pix0 - HALO + tid + off;
                if (lin < base) lin = base;
                if (lin > base + HW4 - 1) lin = base + HW4 - 1;
                const float* frb = fr + (size_t)b * Cc * HW4 + (lin - base);
                float acc = 0.f;
#pragma unroll
                for (int c = 0; c < Cc; ++c)
                    acc = fmaf(wred[Cc + c], frb[(size_t)c * HW4], acc);
                rrow[tid] = acc;
            } else if (tid < RW + PPB) {
                int j = tid - RW;
                int li = pix0 + j - base + off;
                if (li > HW4 - 1) li = HW4 - 1;
                const float* flb = fl + (size_t)b * Cc * HW4 + li;
                float acc = 0.f;
#pragma unroll
                for (int c = 0; c < Cc; ++c)
                    acc = fmaf(wred[c], flb[(size_t)c * HW4], acc);
                lrow[j] = acc;
            }
            __syncthreads();
            L = lrow[plocal];
#pragma unroll
            for (int i = 0; i < DPT; ++i) {
                int d = dbase + i;
                int idx = HALO + plocal - d;
                RR[i] = rrow[(col >= d) ? idx : HALO + plocal];
            }
        } else {
            L = 0.f;
#pragma unroll
            for (int i = 0; i < DPT; ++i) RR[i] = 0.f;
        }

        // ---- u32 monotone order keys ----
        unsigned u[DPT];
#pragma unroll
        for (int i = 0; i < DPT; ++i) {
            unsigned r = __float_as_uint(a[i]);
            u[i] = ((int)r < 0) ? ~r : (r | 0x80000000u);
        }

        // ---- global max ----
        float m = a[0];
#pragma unroll
        for (int i = 1; i < DPT; ++i) m = fmaxf(m, a[i]);
        m = fmaxf(m, lxor_f<1>(m));
        m = fmaxf(m, lxor_f<2>(m));
        m = fmaxf(m, lxor_f<4>(m));

        // ---- beat counts (or ablated selection) ----
        int bc[DPT];
        if constexpr (!(MODE & 1)) {
#pragma unroll
            for (int i = 0; i < DPT; ++i) bc[i] = 0;
#pragma unroll
            for (int i = 0; i < DPT; ++i) {
#pragma unroll
                for (int j = i + 1; j < DPT; ++j) {
                    int c = (u[i] >= u[j]) ? 1 : 0;
                    bc[j] += c;
                    bc[i] += 1 - c;
                }
            }
            rank_round<1>(u, bc, q);
            rank_round<2>(u, bc, q);
            rank_round<3>(u, bc, q);
            rank_round<4>(u, bc, q);
            rank_round<5>(u, bc, q);
            rank_round<6>(u, bc, q);
            rank_round<7>(u, bc, q);
        } else {
#pragma unroll
            for (int i = 0; i < DPT; ++i) {
                asm volatile("" :: "v"(u[i]));       // keep key-gen live
                bc[i] = (dbase + i < Kc) ? 0 : Kc;   // first-24 fake selection
            }
        }

        // ---- per-thread partials ----
        const float NEG = -3.0e38f;
        float s = 0.f, s2 = 0.f, n2 = 0.f;
        float v1 = NEG, v2 = NEG;
        int   i1 = 0,   i2v = 0;
#pragma unroll
        for (int i = 0; i < DPT; ++i) {
            const int d = dbase + i;
            float e = __expf(a[i] - m);
            s += e;
            bool sel = bc[i] < Kc;
            float es = sel ? e : 0.f;
            s2 += es;
            n2 = fmaf(es, (float)d, n2);
            float R = (col >= d) ? RR[i] : 0.f;
            float cst = sel ? e * (L + R) : NEG;
            bool g1 = cst > v1;
            bool g2 = cst > v2;
            float nv2 = g1 ? v1 : (g2 ? cst : v2);
            int   ni2 = g1 ? i1 : (g2 ? d : i2v);
            v1 = g1 ? cst : v1;
            i1 = g1 ? d : i1;
            v2 = nv2;
            i2v = ni2;
        }

        merge_stage<1>(s, s2, n2, v1, i1, v2, i2v);
        merge_stage<2>(s, s2, n2, v1, i1, v2, i2v);
        merge_stage<4>(s, s2, n2, v1, i1, v2, i2v);

        const float r = __expf((v2 - v1) / s);
        accA += n2 / s2;
        accD += ((float)i1 + r * (float)i2v) / (1.f + r);
    }

    if (q == 0) {
        oA4[pix] = accA;
        oD4[pix] = accD;
    }
}

// ---------------------------------------------------------------------------
// Kernel C: identical to R9.
// ---------------------------------------------------------------------------
__global__ __launch_bounds__(256) void k_upsample(const float* __restrict__ spx,
                           const float* __restrict__ A4, const float* __restrict__ D4p,
                           float* __restrict__ oA1, float* __restrict__ oD1) {
    int t = blockIdx.x * blockDim.x + threadIdx.x;
    if (t >= S1 / 4) return;
    const int Wq  = Wc / 4;
    int xg  = t % Wq;
    int rem = t / Wq;
    int y   = rem % Hc;
    int b   = rem / Hc;
    int yx0 = y * Wc + xg * 4;

    const float* sp = spx + (size_t)b * 9 * HW1 + yx0;
    float4 e[9];
    float4 ssum = {0.f, 0.f, 0.f, 0.f};
#pragma unroll
    for (int j = 0; j < 9; ++j) {
        float4 v = *(const float4*)(sp + (size_t)j * HW1);
        e[j].x = __expf(v.x); e[j].y = __expf(v.y);
        e[j].z = __expf(v.z); e[j].w = __expf(v.w);
        ssum.x += e[j].x; ssum.y += e[j].y; ssum.z += e[j].z; ssum.w += e[j].w;
    }

    const int y4 = y >> 2, x4 = xg;
    const float* A4b = A4 + b * HW4;
    const float* D4b = D4p + b * HW4;
    float4 accA = {0.f, 0.f, 0.f, 0.f}, accD = {0.f, 0.f, 0.f, 0.f};
#pragma unroll
    for (int dy = 0; dy < 3; ++dy) {
        int yy = y4 + dy - 1;
#pragma unroll
        for (int dx = 0; dx < 3; ++dx) {
            int xx = x4 + dx - 1;
            int j = dy * 3 + dx;
            bool ok = (yy >= 0 && yy < H4c && xx >= 0 && xx < W4c);
            int pI = ok ? (yy * W4c + xx) : 0;
            float ca = ok ? A4b[pI] : 0.f;
            float cd = ok ? D4b[pI] : 0.f;
            accA.x = fmaf(e[j].x, ca, accA.x); accA.y = fmaf(e[j].y, ca, accA.y);
            accA.z = fmaf(e[j].z, ca, accA.z); accA.w = fmaf(e[j].w, ca, accA.w);
            accD.x = fmaf(e[j].x, cd, accD.x); accD.y = fmaf(e[j].y, cd, accD.y);
            accD.z = fmaf(e[j].z, cd, accD.z); accD.w = fmaf(e[j].w, cd, accD.w);
        }
    }
    float4 inv;
    inv.x = 4.f * __builtin_amdgcn_rcpf(ssum.x);
    inv.y = 4.f * __builtin_amdgcn_rcpf(ssum.y);
    inv.z = 4.f * __builtin_amdgcn_rcpf(ssum.z);
    inv.w = 4.f * __builtin_amdgcn_rcpf(ssum.w);
    float4 oA, oD;
    oA.x = accA.x * inv.x; oA.y = accA.y * inv.y;
    oA.z = accA.z * inv.z; oA.w = accA.w * inv.w;
    oD.x = accD.x * inv.x; oD.y = accD.y * inv.y;
    oD.z = accD.z * inv.z; oD.w = accD.w * inv.w;
    *(float4*)(oA1 + (size_t)b * HW1 + yx0) = oA;
    *(float4*)(oD1 + (size_t)b * HW1 + yx0) = oD;
}

extern "C" void kernel_launch(void* const* d_in, const int* in_sizes, int n_in,
                              void* d_out, int out_size, void* d_ws, size_t ws_size,
                              hipStream_t stream) {
    const float* att  = (const float*)d_in[0];
    const float* fl   = (const float*)d_in[1];
    const float* fr   = (const float*)d_in[2];
    const float* wred = (const float*)d_in[3];
    const float* spx  = (const float*)d_in[4];

    float* out = (float*)d_out;
    float* oA4 = out;
    float* oA1 = out + S4;
    float* oD4 = out + S4 + S1;
    float* oD1 = out + 2 * S4 + S1;

    // ---- MEASUREMENT: x8-amplified ablation variants -> d_ws (surface in
    // rocprof top-5 with their own counters).  Deterministic, outputs unused.
    if (ws_size >= (size_t)2 * S4 * sizeof(float)) {
        float* wA = (float*)d_ws;
        float* wD = wA + S4;
        k_topk_t<0, 8><<<S4 / PPB, 256, 0, stream>>>(att, fl, fr, wred, wA, wD); // FULL x8
        k_topk_t<1, 8><<<S4 / PPB, 256, 0, stream>>>(att, fl, fr, wred, wA, wD); // NORANK x8
        k_topk_t<2, 8><<<S4 / PPB, 256, 0, stream>>>(att, fl, fr, wred, wA, wD); // NOFEAT x8
        k_topk_t<6, 8><<<S4 / PPB, 256, 0, stream>>>(att, fl, fr, wred, wA, wD); // NOLOAD x8
    }

    // ---- real computation (identical to R9 path) ----
    k_topk_t<0, 1><<<S4 / PPB, 256, 0, stream>>>(att, fl, fr, wred, oA4, oD4);
    k_upsample<<<(S1 / 4 + 255) / 256, 256, 0, stream>>>(spx, oA4, oD4, oA1, oD1);
}

// Round 11
// 164.441 us; speedup vs baseline: 2.2399x; 2.2399x over previous
//
#include <hip/hip_runtime.h>
#include <hip/hip_bf16.h>
#include <math.h>

#define Bc 2
#define Cc 16
#define D4c 48
#define Kc 24
#define Hc 512
#define Wc 960
#define H4c 128
#define W4c 240
#define HW4 (H4c * W4c)   // 30720
#define S4 (Bc * HW4)     // 61440
#define HW1 (Hc * Wc)     // 491520
#define S1 (Bc * HW1)     // 983040
#define Gg 8              // disparity groups (lanes per pixel)
#define DPT 6             // disparities per thread
#define PPB 32            // pixels per block
#define HALO 47           // max disparity reach to the left
#define RW (PPB + HALO)   // 79: Rred halo row length

// ---------------------------------------------------------------------------
// Cross-lane helpers.  Group dim in lane bits [2:0].
// xor1/2/3: single v_mov_b32_dpp (quad_perm).  xor4: ds_swizzle (DS pipe,
// prefetchable) or 2-instr DPP pair (for the once-per-rep merge).
// ---------------------------------------------------------------------------
template<int X>
__device__ __forceinline__ unsigned lxor_dpp(unsigned v) {
    static_assert(X >= 1 && X <= 3, "quad-perm range");
    constexpr int ctrl = (X == 1) ? 0xB1 : (X == 2) ? 0x4E : 0x1B;
    return (unsigned)__builtin_amdgcn_mov_dpp((int)v, ctrl, 0xF, 0xF, true);
}
__device__ __forceinline__ unsigned lxor4_pair(unsigned v) {
    int r = (int)v;
    int t = __builtin_amdgcn_update_dpp(r, r, 0x104, 0xF, 0x5, false); // row_shl:4, banks 0,2
    r     = __builtin_amdgcn_update_dpp(t, r, 0x114, 0xF, 0xA, false); // row_shr:4, banks 1,3
    return (unsigned)r;
}
__device__ __forceinline__ unsigned swz_xor4(unsigned v) {
    return (unsigned)__builtin_amdgcn_ds_swizzle((int)v, 0x101F);     // lane ^= 4
}

template<int X> __device__ __forceinline__ float lxf(float v) {
    if constexpr (X == 4) return __uint_as_float(lxor4_pair(__float_as_uint(v)));
    else                  return __uint_as_float(lxor_dpp<X>(__float_as_uint(v)));
}
template<int X> __device__ __forceinline__ int lxi(int v) {
    if constexpr (X == 4) return (int)lxor4_pair((unsigned)v);
    else                  return (int)lxor_dpp<X>((unsigned)v);
}

// accumulate bc[i] += #{j : uj[j] > u[i] - adj(C,q)}
template<int C>
__device__ __forceinline__ void rank_vs(const unsigned (&uj)[DPT], const unsigned (&u)[DPT],
                                        int (&bc)[DPT], int q) {
    const unsigned adj = ((q ^ C) < q) ? 1u : 0u;
#pragma unroll
    for (int i = 0; i < DPT; ++i) {
        const unsigned ui2 = u[i] - adj;
#pragma unroll
        for (int j = 0; j < DPT; ++j) bc[i] += (uj[j] > ui2) ? 1 : 0;
    }
}

template<int X>
__device__ __forceinline__ void merge_stage(float& s, float& s2, float& n2,
                                            float& v1, int& i1, float& v2, int& i2v) {
    s  += lxf<X>(s);
    s2 += lxf<X>(s2);
    n2 += lxf<X>(n2);
    float ov1 = lxf<X>(v1); int oi1 = lxi<X>(i1);
    float ov2 = lxf<X>(v2); int oi2 = lxi<X>(i2v);
    bool bt = (ov1 > v1) || (ov1 == v1 && oi1 < i1);
    float w1 = bt ? ov1 : v1;   int wi1 = bt ? oi1 : i1;
    float l1 = bt ? v1  : ov1;  int li1 = bt ? i1  : oi1;
    float w2 = bt ? ov2 : v2;   int wi2 = bt ? oi2 : i2v;
    bool b2 = (l1 > w2) || (l1 == w2 && li1 < wi2);
    v1 = w1; i1 = wi1;
    v2 = b2 ? l1 : w2;
    i2v = b2 ? li1 : wi2;
}

// ---------------------------------------------------------------------------
// MODE: 0 = full, 1 = rank loop ablated (keys kept live).  REP>1: amplified
// probe with asm-opaque offset (defeats CSE), for rocprof visibility.
// ---------------------------------------------------------------------------
template<int MODE, int REP>
__global__ __launch_bounds__(256, 6) void k_topk_t(const float* __restrict__ att,
                       const float* __restrict__ fl, const float* __restrict__ fr,
                       const float* __restrict__ wred,
                       float* __restrict__ oA4, float* __restrict__ oD4) {
    __shared__ float rrow[RW];
    __shared__ float lrow[PPB];

    const int tid    = threadIdx.x;
    const int wv     = tid >> 6;
    const int lane   = tid & 63;
    const int q      = lane & 7;      // disparity group (lane bits [2:0] => DPP)
    const int p      = lane >> 3;     // pixel within wave
    const int plocal = wv * 8 + p;    // 0..31
    const int pix0   = blockIdx.x * PPB;
    const int pix    = pix0 + plocal;
    const int b      = pix0 / HW4;    // uniform per block (HW4 % 32 == 0)
    const int hw     = pix - b * HW4;
    const int col    = hw % W4c;
    const int dbase  = q * DPT;

    float accA = 0.f, accD = 0.f;
#pragma unroll 1
    for (int rep = 0; rep < REP; ++rep) {
        int off = 0;
        if constexpr (REP > 1) {
            asm volatile("v_mov_b32 %0, %1" : "=v"(off) : "v"(rep));
        }
        int hw2 = hw + off; if (hw2 >= HW4) hw2 = HW4 - 1;

        // ---- att logits ----
        const float* ap = att + ((size_t)b * D4c + dbase) * HW4 + hw2;
        float a[DPT];
#pragma unroll
        for (int i = 0; i < DPT; ++i) a[i] = ap[(size_t)i * HW4];

        // ---- feat channel-reduction into LDS (waves 0,1 -> rrow; wave 2 -> lrow)
        if constexpr (REP > 1) __syncthreads();   // protect rrow reuse across reps
        {
            const int base = b * HW4;
            if (tid < RW) {
                int lin = pix0 - HALO + tid + off;
                if (lin < base) lin = base;
                if (lin > base + HW4 - 1) lin = base + HW4 - 1;
                const float* frb = fr + (size_t)b * Cc * HW4 + (lin - base);
                float a0 = 0.f, a1 = 0.f;
#pragma unroll
                for (int c = 0; c < Cc / 2; ++c) {
                    a0 = fmaf(wred[Cc + c],          frb[(size_t)c * HW4], a0);
                    a1 = fmaf(wred[Cc + Cc / 2 + c], frb[(size_t)(Cc / 2 + c) * HW4], a1);
                }
                rrow[tid] = a0 + a1;
            } else if (tid >= 128 && tid < 128 + PPB) {
                int j = tid - 128;
                int li = pix0 + j - base + off;
                if (li > HW4 - 1) li = HW4 - 1;
                const float* flb = fl + (size_t)b * Cc * HW4 + li;
                float a0 = 0.f, a1 = 0.f;
#pragma unroll
                for (int c = 0; c < Cc / 2; ++c) {
                    a0 = fmaf(wred[c],          flb[(size_t)c * HW4], a0);
                    a1 = fmaf(wred[Cc / 2 + c], flb[(size_t)(Cc / 2 + c) * HW4], a1);
                }
                lrow[j] = a0 + a1;
            }
        }
        __syncthreads();

        const float L = lrow[plocal];
        float RR[DPT];
#pragma unroll
        for (int i = 0; i < DPT; ++i)
            RR[i] = rrow[HALO + plocal - (dbase + i)];   // always in [0,78]

        // ---- u32 monotone order keys ----
        unsigned u[DPT];
#pragma unroll
        for (int i = 0; i < DPT; ++i) {
            unsigned r = __float_as_uint(a[i]);
            u[i] = ((int)r < 0) ? ~r : (r | 0x80000000u);
        }

        // ---- beat counts (exact top-24 selection) ----
        int bc[DPT];
        if constexpr (!(MODE & 1)) {
#pragma unroll
            for (int i = 0; i < DPT; ++i) bc[i] = 0;
            // u4 = keys from lane^4, via DS swizzle issued EARLY (latency
            // hides under rounds 1-3 on the VALU)
            unsigned u4[DPT];
#pragma unroll
            for (int j = 0; j < DPT; ++j) u4[j] = swz_xor4(u[j]);
            // own group: 15 pairs, i beats j iff u[i] >= u[j]
#pragma unroll
            for (int i = 0; i < DPT; ++i) {
#pragma unroll
                for (int j = i + 1; j < DPT; ++j) {
                    int c = (u[i] >= u[j]) ? 1 : 0;
                    bc[j] += c;
                    bc[i] += 1 - c;
                }
            }
            {   unsigned t[DPT];
#pragma unroll
                for (int j = 0; j < DPT; ++j) t[j] = lxor_dpp<1>(u[j]);
                rank_vs<1>(t, u, bc, q);
            }
            {   unsigned t[DPT];
#pragma unroll
                for (int j = 0; j < DPT; ++j) t[j] = lxor_dpp<2>(u[j]);
                rank_vs<2>(t, u, bc, q);
            }
            {   unsigned t[DPT];
#pragma unroll
                for (int j = 0; j < DPT; ++j) t[j] = lxor_dpp<3>(u[j]);
                rank_vs<3>(t, u, bc, q);
            }
            rank_vs<4>(u4, u, bc, q);
            {   unsigned t[DPT];
#pragma unroll
                for (int j = 0; j < DPT; ++j) t[j] = lxor_dpp<1>(u4[j]);
                rank_vs<5>(t, u, bc, q);
            }
            {   unsigned t[DPT];
#pragma unroll
                for (int j = 0; j < DPT; ++j) t[j] = lxor_dpp<2>(u4[j]);
                rank_vs<6>(t, u, bc, q);
            }
            {   unsigned t[DPT];
#pragma unroll
                for (int j = 0; j < DPT; ++j) t[j] = lxor_dpp<3>(u4[j]);
                rank_vs<7>(t, u, bc, q);
            }
        } else {
#pragma unroll
            for (int i = 0; i < DPT; ++i) {
                asm volatile("" :: "v"(u[i]));       // keep key-gen live
                bc[i] = (dbase + i < Kc) ? 0 : Kc;   // fake first-24 selection
            }
        }

        // ---- per-thread partials (no max-sub: softmax is scale-invariant,
        // logits ~N(0,1) so exp(a) is safely in fp32 range) ----
        const float NEG = -3.0e38f;
        float s = 0.f, s2 = 0.f, n2 = 0.f;
        float v1 = NEG, v2 = NEG;
        int   i1 = 0,   i2v = 0;
#pragma unroll
        for (int i = 0; i < DPT; ++i) {
            const int d = dbase + i;
            float e = __expf(a[i]);
            s += e;
            bool sel = bc[i] < Kc;
            float es = sel ? e : 0.f;
            s2 += es;
            n2 = fmaf(es, (float)d, n2);
            float R = (col >= d) ? RR[i] : 0.f;
            float cst = sel ? e * (L + R) : NEG;
            bool g1 = cst > v1;
            bool g2 = cst > v2;
            float nv2 = g1 ? v1 : (g2 ? cst : v2);
            int   ni2 = g1 ? i1 : (g2 ? d : i2v);
            v1 = g1 ? cst : v1;
            i1 = g1 ? d : i1;
            v2 = nv2;
            i2v = ni2;
        }

        merge_stage<1>(s, s2, n2, v1, i1, v2, i2v);
        merge_stage<2>(s, s2, n2, v1, i1, v2, i2v);
        merge_stage<4>(s, s2, n2, v1, i1, v2, i2v);

        const float r = __expf((v2 - v1) * __builtin_amdgcn_rcpf(s));
        accA += n2 * __builtin_amdgcn_rcpf(s2);
        accD += fmaf(r, (float)i2v, (float)i1) * __builtin_amdgcn_rcpf(1.f + r);
    }

    if (q == 0) {
        oA4[pix] = accA;
        oD4[pix] = accD;
    }
}

// ---------------------------------------------------------------------------
// Kernel C: identical to R9.
// ---------------------------------------------------------------------------
__global__ __launch_bounds__(256) void k_upsample(const float* __restrict__ spx,
                           const float* __restrict__ A4, const float* __restrict__ D4p,
                           float* __restrict__ oA1, float* __restrict__ oD1) {
    int t = blockIdx.x * blockDim.x + threadIdx.x;
    if (t >= S1 / 4) return;
    const int Wq  = Wc / 4;
    int xg  = t % Wq;
    int rem = t / Wq;
    int y   = rem % Hc;
    int b   = rem / Hc;
    int yx0 = y * Wc + xg * 4;

    const float* sp = spx + (size_t)b * 9 * HW1 + yx0;
    float4 e[9];
    float4 ssum = {0.f, 0.f, 0.f, 0.f};
#pragma unroll
    for (int j = 0; j < 9; ++j) {
        float4 v = *(const float4*)(sp + (size_t)j * HW1);
        e[j].x = __expf(v.x); e[j].y = __expf(v.y);
        e[j].z = __expf(v.z); e[j].w = __expf(v.w);
        ssum.x += e[j].x; ssum.y += e[j].y; ssum.z += e[j].z; ssum.w += e[j].w;
    }

    const int y4 = y >> 2, x4 = xg;
    const float* A4b = A4 + b * HW4;
    const float* D4b = D4p + b * HW4;
    float4 accA = {0.f, 0.f, 0.f, 0.f}, accD = {0.f, 0.f, 0.f, 0.f};
#pragma unroll
    for (int dy = 0; dy < 3; ++dy) {
        int yy = y4 + dy - 1;
#pragma unroll
        for (int dx = 0; dx < 3; ++dx) {
            int xx = x4 + dx - 1;
            int j = dy * 3 + dx;
            bool ok = (yy >= 0 && yy < H4c && xx >= 0 && xx < W4c);
            int pI = ok ? (yy * W4c + xx) : 0;
            float ca = ok ? A4b[pI] : 0.f;
            float cd = ok ? D4b[pI] : 0.f;
            accA.x = fmaf(e[j].x, ca, accA.x); accA.y = fmaf(e[j].y, ca, accA.y);
            accA.z = fmaf(e[j].z, ca, accA.z); accA.w = fmaf(e[j].w, ca, accA.w);
            accD.x = fmaf(e[j].x, cd, accD.x); accD.y = fmaf(e[j].y, cd, accD.y);
            accD.z = fmaf(e[j].z, cd, accD.z); accD.w = fmaf(e[j].w, cd, accD.w);
        }
    }
    float4 inv;
    inv.x = 4.f * __builtin_amdgcn_rcpf(ssum.x);
    inv.y = 4.f * __builtin_amdgcn_rcpf(ssum.y);
    inv.z = 4.f * __builtin_amdgcn_rcpf(ssum.z);
    inv.w = 4.f * __builtin_amdgcn_rcpf(ssum.w);
    float4 oA, oD;
    oA.x = accA.x * inv.x; oA.y = accA.y * inv.y;
    oA.z = accA.z * inv.z; oA.w = accA.w * inv.w;
    oD.x = accD.x * inv.x; oD.y = accD.y * inv.y;
    oD.z = accD.z * inv.z; oD.w = accD.w * inv.w;
    *(float4*)(oA1 + (size_t)b * HW1 + yx0) = oA;
    *(float4*)(oD1 + (size_t)b * HW1 + yx0) = oD;
}

extern "C" void kernel_launch(void* const* d_in, const int* in_sizes, int n_in,
                              void* d_out, int out_size, void* d_ws, size_t ws_size,
                              hipStream_t stream) {
    const float* att  = (const float*)d_in[0];
    const float* fl   = (const float*)d_in[1];
    const float* fr   = (const float*)d_in[2];
    const float* wred = (const float*)d_in[3];
    const float* spx  = (const float*)d_in[4];

    float* out = (float*)d_out;
    float* oA4 = out;
    float* oA1 = out + S4;
    float* oD4 = out + S4 + S1;
    float* oD1 = out + 2 * S4 + S1;

    // ---- PROBE: NORANK x32 -> d_ws.  Its rocprof row gives the non-rank
    // cost per rep; R = FULL_new - row_dur/32.  Deterministic, output-unused.
    if (ws_size >= (size_t)2 * S4 * sizeof(float)) {
        float* wA = (float*)d_ws;
        float* wD = wA + S4;
        k_topk_t<1, 32><<<S4 / PPB, 256, 0, stream>>>(att, fl, fr, wred, wA, wD);
    }

    // ---- real path ----
    k_topk_t<0, 1><<<S4 / PPB, 256, 0, stream>>>(att, fl, fr, wred, oA4, oD4);
    k_upsample<<<(S1 / 4 + 255) / 256, 256, 0, stream>>>(spx, oA4, oD4, oA1, oD1);
}

// Round 12
// 29.124 us; speedup vs baseline: 12.6473x; 5.6463x over previous
//
#include <hip/hip_runtime.h>
#include <hip/hip_bf16.h>
#include <math.h>

#define Bc 2
#define Cc 16
#define D4c 48
#define Kc 24
#define Hc 512
#define Wc 960
#define H4c 128
#define W4c 240
#define HW4 (H4c * W4c)   // 30720
#define S4 (Bc * HW4)     // 61440
#define HW1 (Hc * Wc)     // 491520
#define S1 (Bc * HW1)     // 983040
#define Gg 8              // disparity groups (lanes per pixel)
#define DPT 6             // disparities per thread
#define PPB 32            // pixels per block
#define HALO 47           // max disparity reach to the left
#define RW (PPB + HALO)   // 79: Rred halo row length

// ---------------------------------------------------------------------------
// Cross-lane helpers.  Group dim in lane bits [2:0].
// xor1/2/3: single v_mov_b32_dpp (quad_perm).  xor4: ds_swizzle (DS pipe,
// prefetchable) or 2-instr DPP pair (for the once-per-pixel merge).
// ---------------------------------------------------------------------------
template<int X>
__device__ __forceinline__ unsigned lxor_dpp(unsigned v) {
    static_assert(X >= 1 && X <= 3, "quad-perm range");
    constexpr int ctrl = (X == 1) ? 0xB1 : (X == 2) ? 0x4E : 0x1B;
    return (unsigned)__builtin_amdgcn_mov_dpp((int)v, ctrl, 0xF, 0xF, true);
}
__device__ __forceinline__ unsigned lxor4_pair(unsigned v) {
    int r = (int)v;
    int t = __builtin_amdgcn_update_dpp(r, r, 0x104, 0xF, 0x5, false); // row_shl:4, banks 0,2
    r     = __builtin_amdgcn_update_dpp(t, r, 0x114, 0xF, 0xA, false); // row_shr:4, banks 1,3
    return (unsigned)r;
}
__device__ __forceinline__ unsigned swz_xor4(unsigned v) {
    return (unsigned)__builtin_amdgcn_ds_swizzle((int)v, 0x101F);     // lane ^= 4
}

template<int X> __device__ __forceinline__ float lxf(float v) {
    if constexpr (X == 4) return __uint_as_float(lxor4_pair(__float_as_uint(v)));
    else                  return __uint_as_float(lxor_dpp<X>(__float_as_uint(v)));
}
template<int X> __device__ __forceinline__ int lxi(int v) {
    if constexpr (X == 4) return (int)lxor4_pair((unsigned)v);
    else                  return (int)lxor_dpp<X>((unsigned)v);
}

// accumulate bc[i] += #{j : uj[j] > u[i] - adj(C,q)}
template<int C>
__device__ __forceinline__ void rank_vs(const unsigned (&uj)[DPT], const unsigned (&u)[DPT],
                                        int (&bc)[DPT], int q) {
    const unsigned adj = ((q ^ C) < q) ? 1u : 0u;
#pragma unroll
    for (int i = 0; i < DPT; ++i) {
        const unsigned ui2 = u[i] - adj;
#pragma unroll
        for (int j = 0; j < DPT; ++j) bc[i] += (uj[j] > ui2) ? 1 : 0;
    }
}

template<int X>
__device__ __forceinline__ void merge_stage(float& s, float& s2, float& n2,
                                            float& v1, int& i1, float& v2, int& i2v) {
    s  += lxf<X>(s);
    s2 += lxf<X>(s2);
    n2 += lxf<X>(n2);
    float ov1 = lxf<X>(v1); int oi1 = lxi<X>(i1);
    float ov2 = lxf<X>(v2); int oi2 = lxi<X>(i2v);
    bool bt = (ov1 > v1) || (ov1 == v1 && oi1 < i1);
    float w1 = bt ? ov1 : v1;   int wi1 = bt ? oi1 : i1;
    float l1 = bt ? v1  : ov1;  int li1 = bt ? i1  : oi1;
    float w2 = bt ? ov2 : v2;   int wi2 = bt ? oi2 : i2v;
    bool b2 = (l1 > w2) || (l1 == w2 && li1 < wi2);
    v1 = w1; i1 = wi1;
    v2 = b2 ? l1 : w2;
    i2v = b2 ? li1 : wi2;
}

// ---------------------------------------------------------------------------
// Fused topk kernel (identical to R11 real path).
// ---------------------------------------------------------------------------
__global__ __launch_bounds__(256, 6) void k_topk(const float* __restrict__ att,
                       const float* __restrict__ fl, const float* __restrict__ fr,
                       const float* __restrict__ wred,
                       float* __restrict__ oA4, float* __restrict__ oD4) {
    __shared__ float rrow[RW];
    __shared__ float lrow[PPB];

    const int tid    = threadIdx.x;
    const int wv     = tid >> 6;
    const int lane   = tid & 63;
    const int q      = lane & 7;      // disparity group (lane bits [2:0] => DPP)
    const int p      = lane >> 3;     // pixel within wave
    const int plocal = wv * 8 + p;    // 0..31
    const int pix0   = blockIdx.x * PPB;
    const int pix    = pix0 + plocal;
    const int b      = pix0 / HW4;    // uniform per block (HW4 % 32 == 0)
    const int hw     = pix - b * HW4;
    const int col    = hw % W4c;
    const int dbase  = q * DPT;

    // ---- att logits ----
    const float* ap = att + ((size_t)b * D4c + dbase) * HW4 + hw;
    float a[DPT];
#pragma unroll
    for (int i = 0; i < DPT; ++i) a[i] = ap[(size_t)i * HW4];

    // ---- feat channel-reduction into LDS (waves 0,1 -> rrow; wave 2 -> lrow)
    {
        const int base = b * HW4;
        if (tid < RW) {
            int lin = pix0 - HALO + tid;
            if (lin < base) lin = base;            // clamped values never used
            const float* frb = fr + (size_t)b * Cc * HW4 + (lin - base);
            float a0 = 0.f, a1 = 0.f;
#pragma unroll
            for (int c = 0; c < Cc / 2; ++c) {
                a0 = fmaf(wred[Cc + c],          frb[(size_t)c * HW4], a0);
                a1 = fmaf(wred[Cc + Cc / 2 + c], frb[(size_t)(Cc / 2 + c) * HW4], a1);
            }
            rrow[tid] = a0 + a1;
        } else if (tid >= 128 && tid < 128 + PPB) {
            int j = tid - 128;
            const float* flb = fl + (size_t)b * Cc * HW4 + (pix0 + j - base);
            float a0 = 0.f, a1 = 0.f;
#pragma unroll
            for (int c = 0; c < Cc / 2; ++c) {
                a0 = fmaf(wred[c],          flb[(size_t)c * HW4], a0);
                a1 = fmaf(wred[Cc / 2 + c], flb[(size_t)(Cc / 2 + c) * HW4], a1);
            }
            lrow[j] = a0 + a1;
        }
    }
    __syncthreads();

    const float L = lrow[plocal];
    float RR[DPT];
#pragma unroll
    for (int i = 0; i < DPT; ++i)
        RR[i] = rrow[HALO + plocal - (dbase + i)];   // always in [0,78]

    // ---- u32 monotone order keys ----
    unsigned u[DPT];
#pragma unroll
    for (int i = 0; i < DPT; ++i) {
        unsigned r = __float_as_uint(a[i]);
        u[i] = ((int)r < 0) ? ~r : (r | 0x80000000u);
    }

    // ---- beat counts (exact top-24 selection) ----
    int bc[DPT];
#pragma unroll
    for (int i = 0; i < DPT; ++i) bc[i] = 0;
    // u4 = keys from lane^4, via DS swizzle issued EARLY (latency hides
    // under rounds 1-3 on the VALU)
    unsigned u4[DPT];
#pragma unroll
    for (int j = 0; j < DPT; ++j) u4[j] = swz_xor4(u[j]);
    // own group: 15 pairs, i beats j iff u[i] >= u[j]
#pragma unroll
    for (int i = 0; i < DPT; ++i) {
#pragma unroll
        for (int j = i + 1; j < DPT; ++j) {
            int c = (u[i] >= u[j]) ? 1 : 0;
            bc[j] += c;
            bc[i] += 1 - c;
        }
    }
    {   unsigned t[DPT];
#pragma unroll
        for (int j = 0; j < DPT; ++j) t[j] = lxor_dpp<1>(u[j]);
        rank_vs<1>(t, u, bc, q);
    }
    {   unsigned t[DPT];
#pragma unroll
        for (int j = 0; j < DPT; ++j) t[j] = lxor_dpp<2>(u[j]);
        rank_vs<2>(t, u, bc, q);
    }
    {   unsigned t[DPT];
#pragma unroll
        for (int j = 0; j < DPT; ++j) t[j] = lxor_dpp<3>(u[j]);
        rank_vs<3>(t, u, bc, q);
    }
    rank_vs<4>(u4, u, bc, q);
    {   unsigned t[DPT];
#pragma unroll
        for (int j = 0; j < DPT; ++j) t[j] = lxor_dpp<1>(u4[j]);
        rank_vs<5>(t, u, bc, q);
    }
    {   unsigned t[DPT];
#pragma unroll
        for (int j = 0; j < DPT; ++j) t[j] = lxor_dpp<2>(u4[j]);
        rank_vs<6>(t, u, bc, q);
    }
    {   unsigned t[DPT];
#pragma unroll
        for (int j = 0; j < DPT; ++j) t[j] = lxor_dpp<3>(u4[j]);
        rank_vs<7>(t, u, bc, q);
    }

    // ---- per-thread partials (no max-sub: softmax is scale-invariant,
    // logits ~N(0,1) so exp(a) is safely in fp32 range) ----
    const float NEG = -3.0e38f;
    float s = 0.f, s2 = 0.f, n2 = 0.f;
    float v1 = NEG, v2 = NEG;
    int   i1 = 0,   i2v = 0;
#pragma unroll
    for (int i = 0; i < DPT; ++i) {
        const int d = dbase + i;
        float e = __expf(a[i]);
        s += e;
        bool sel = bc[i] < Kc;
        float es = sel ? e : 0.f;
        s2 += es;
        n2 = fmaf(es, (float)d, n2);
        float R = (col >= d) ? RR[i] : 0.f;
        float cst = sel ? e * (L + R) : NEG;
        bool g1 = cst > v1;
        bool g2 = cst > v2;
        float nv2 = g1 ? v1 : (g2 ? cst : v2);
        int   ni2 = g1 ? i1 : (g2 ? d : i2v);
        v1 = g1 ? cst : v1;
        i1 = g1 ? d : i1;
        v2 = nv2;
        i2v = ni2;
    }

    merge_stage<1>(s, s2, n2, v1, i1, v2, i2v);
    merge_stage<2>(s, s2, n2, v1, i1, v2, i2v);
    merge_stage<4>(s, s2, n2, v1, i1, v2, i2v);

    const float r = __expf((v2 - v1) * __builtin_amdgcn_rcpf(s));
    if (q == 0) {
        oA4[pix] = n2 * __builtin_amdgcn_rcpf(s2);
        oD4[pix] = fmaf(r, (float)i2v, (float)i1) * __builtin_amdgcn_rcpf(1.f + r);
    }
}

// ---------------------------------------------------------------------------
// Kernel C: superpixel-guided 4x upsample (identical to R9/R11).
// ---------------------------------------------------------------------------
__global__ __launch_bounds__(256) void k_upsample(const float* __restrict__ spx,
                           const float* __restrict__ A4, const float* __restrict__ D4p,
                           float* __restrict__ oA1, float* __restrict__ oD1) {
    int t = blockIdx.x * blockDim.x + threadIdx.x;
    if (t >= S1 / 4) return;
    const int Wq  = Wc / 4;
    int xg  = t % Wq;
    int rem = t / Wq;
    int y   = rem % Hc;
    int b   = rem / Hc;
    int yx0 = y * Wc + xg * 4;

    const float* sp = spx + (size_t)b * 9 * HW1 + yx0;
    float4 e[9];
    float4 ssum = {0.f, 0.f, 0.f, 0.f};
#pragma unroll
    for (int j = 0; j < 9; ++j) {
        float4 v = *(const float4*)(sp + (size_t)j * HW1);
        e[j].x = __expf(v.x); e[j].y = __expf(v.y);
        e[j].z = __expf(v.z); e[j].w = __expf(v.w);
        ssum.x += e[j].x; ssum.y += e[j].y; ssum.z += e[j].z; ssum.w += e[j].w;
    }

    const int y4 = y >> 2, x4 = xg;
    const float* A4b = A4 + b * HW4;
    const float* D4b = D4p + b * HW4;
    float4 accA = {0.f, 0.f, 0.f, 0.f}, accD = {0.f, 0.f, 0.f, 0.f};
#pragma unroll
    for (int dy = 0; dy < 3; ++dy) {
        int yy = y4 + dy - 1;
#pragma unroll
        for (int dx = 0; dx < 3; ++dx) {
            int xx = x4 + dx - 1;
            int j = dy * 3 + dx;
            bool ok = (yy >= 0 && yy < H4c && xx >= 0 && xx < W4c);
            int pI = ok ? (yy * W4c + xx) : 0;
            float ca = ok ? A4b[pI] : 0.f;
            float cd = ok ? D4b[pI] : 0.f;
            accA.x = fmaf(e[j].x, ca, accA.x); accA.y = fmaf(e[j].y, ca, accA.y);
            accA.z = fmaf(e[j].z, ca, accA.z); accA.w = fmaf(e[j].w, ca, accA.w);
            accD.x = fmaf(e[j].x, cd, accD.x); accD.y = fmaf(e[j].y, cd, accD.y);
            accD.z = fmaf(e[j].z, cd, accD.z); accD.w = fmaf(e[j].w, cd, accD.w);
        }
    }
    float4 inv;
    inv.x = 4.f * __builtin_amdgcn_rcpf(ssum.x);
    inv.y = 4.f * __builtin_amdgcn_rcpf(ssum.y);
    inv.z = 4.f * __builtin_amdgcn_rcpf(ssum.z);
    inv.w = 4.f * __builtin_amdgcn_rcpf(ssum.w);
    float4 oA, oD;
    oA.x = accA.x * inv.x; oA.y = accA.y * inv.y;
    oA.z = accA.z * inv.z; oA.w = accA.w * inv.w;
    oD.x = accD.x * inv.x; oD.y = accD.y * inv.y;
    oD.z = accD.z * inv.z; oD.w = accD.w * inv.w;
    *(float4*)(oA1 + (size_t)b * HW1 + yx0) = oA;
    *(float4*)(oD1 + (size_t)b * HW1 + yx0) = oD;
}

extern "C" void kernel_launch(void* const* d_in, const int* in_sizes, int n_in,
                              void* d_out, int out_size, void* d_ws, size_t ws_size,
                              hipStream_t stream) {
    const float* att  = (const float*)d_in[0];
    const float* fl   = (const float*)d_in[1];
    const float* fr   = (const float*)d_in[2];
    const float* wred = (const float*)d_in[3];
    const float* spx  = (const float*)d_in[4];

    float* out = (float*)d_out;
    float* oA4 = out;
    float* oA1 = out + S4;
    float* oD4 = out + S4 + S1;
    float* oD1 = out + 2 * S4 + S1;

    k_topk<<<S4 / PPB, 256, 0, stream>>>(att, fl, fr, wred, oA4, oD4);
    k_upsample<<<(S1 / 4 + 255) / 256, 256, 0, stream>>>(spx, oA4, oD4, oA1, oD1);
}